// Round 15
// baseline (75.747 us; speedup 1.0000x reference)
//
#include <hip/hip_runtime.h>
#include <hip/hip_bf16.h>

#define BB 8
#define SS 128
#define HID 768
#define DEP 64
#define DSZ 768
#define NT 45
#define NTP 48
#define NEG -1000000000.0f

typedef short bfv8 __attribute__((ext_vector_type(8)));
typedef float f32x4 __attribute__((ext_vector_type(4)));

__device__ __forceinline__ unsigned short f2bf(float x) {
    unsigned int u; __builtin_memcpy(&u, &x, 4);
    u += 0x7fffu + ((u >> 16) & 1u);
    return (unsigned short)(u >> 16);
}
__device__ __forceinline__ float bf2f(unsigned short h) {
    unsigned int u = ((unsigned int)h) << 16;
    float f; __builtin_memcpy(&f, &u, 4);
    return f;
}

// async global->LDS, 16B per lane; LDS dest is wave-uniform base.
__device__ __forceinline__ void gld16(const unsigned short* gp, unsigned short* lp) {
    typedef __attribute__((address_space(1))) const unsigned int GU;
    typedef __attribute__((address_space(3))) unsigned int LU;
    __builtin_amdgcn_global_load_lds((GU*)(uintptr_t)gp,
                                     (LU*)(unsigned int)(uintptr_t)lp, 16, 0, 0);
}

// ---------------------------------------------------------------------------
// convec: conversions + E/c, one launch. Grid (24, 24, 13):
//   z<4: weight z -> transposed hi (lo for W1/W2), ushort4 stores
//   4<=z<12: h batch b=z-4 (y<4): elementwise float4 -> 2x ushort4
//   z==12: ec blocks (y<2, idx<45): E hi/lo + cv
__global__ __launch_bounds__(256) void convec(
    const float* __restrict__ h, const float* __restrict__ table,
    const float* __restrict__ W1, const float* __restrict__ W2,
    const float* __restrict__ gcn, const float* __restrict__ Wo,
    unsigned short* __restrict__ hHi, unsigned short* __restrict__ hLo,
    unsigned short* __restrict__ WtHi, unsigned short* __restrict__ WtLo,
    unsigned short* __restrict__ gTHi, unsigned short* __restrict__ oTHi,
    unsigned short* __restrict__ Ehi, unsigned short* __restrict__ Elo,
    float* __restrict__ cv) {
    const long WN = (long)DSZ * HID;
    int z = blockIdx.z;
    if (z < 4) {
        __shared__ float tile[32][33];
        int tr = threadIdx.x >> 5, tc = threadIdx.x & 31;
        const float* src = z == 0 ? W1 : z == 1 ? W2 : z == 2 ? gcn : Wo;
        unsigned short* dhi = z == 0 ? WtHi : z == 1 ? WtHi + WN
                            : z == 2 ? gTHi : oTHi;
        unsigned short* dlo = z == 0 ? WtLo : z == 1 ? WtLo + WN : nullptr;
        int r0 = blockIdx.y * 32, c0 = blockIdx.x * 32;
#pragma unroll
        for (int k = 0; k < 4; ++k)
            tile[tr + k * 8][tc] = src[(long)(r0 + tr + k * 8) * 768 + c0 + tc];
        __syncthreads();
        // vectorized transposed write: thread -> (i = tid>>3, 4 j's at (tid&7)*4)
        int i = threadIdx.x >> 3, j4 = (threadIdx.x & 7) << 2;
        float v0 = tile[j4 + 0][i], v1 = tile[j4 + 1][i];
        float v2 = tile[j4 + 2][i], v3 = tile[j4 + 3][i];
        ushort4 hv;
        hv.x = f2bf(v0); hv.y = f2bf(v1); hv.z = f2bf(v2); hv.w = f2bf(v3);
        long o = (long)(c0 + i) * 768 + r0 + j4;
        *(ushort4*)(dhi + o) = hv;
        if (dlo) {
            ushort4 lv;
            lv.x = f2bf(v0 - bf2f(hv.x)); lv.y = f2bf(v1 - bf2f(hv.y));
            lv.z = f2bf(v2 - bf2f(hv.z)); lv.w = f2bf(v3 - bf2f(hv.w));
            *(ushort4*)(dlo + o) = lv;
        }
    } else if (z < 12) {
        if (blockIdx.y >= 4) return;
        int b = z - 4;
        // elementwise: 96 blocks x 256 thr x 1 float4 = 98304 floats = SS*HID
        long idx = ((long)(blockIdx.y * 24 + blockIdx.x) * 256 + threadIdx.x);
        const float* Xb = h + (long)b * SS * HID;
        float4 v = ((const float4*)Xb)[idx];
        ushort4 hv, lv;
        hv.x = f2bf(v.x); lv.x = f2bf(v.x - bf2f(hv.x));
        hv.y = f2bf(v.y); lv.y = f2bf(v.y - bf2f(hv.y));
        hv.z = f2bf(v.z); lv.z = f2bf(v.z - bf2f(hv.z));
        hv.w = f2bf(v.w); lv.w = f2bf(v.w - bf2f(hv.w));
        long o = (long)b * SS * HID / 4 + idx;
        ((ushort4*)hHi)[o] = hv;
        ((ushort4*)hLo)[o] = lv;
    } else {
        if (blockIdx.y >= 2) return;
        int t = blockIdx.y * 24 + blockIdx.x;
        if (t >= NT) return;
        const long EN = (long)NTP * DSZ;
        __shared__ float tl[DEP];
        __shared__ float red[256];
        for (int d = threadIdx.x; d < DEP; d += 256) tl[d] = table[t * DEP + d];
        __syncthreads();
        float dotacc = 0.f;
#pragma unroll
        for (int k = 0; k < 3; ++k) {
            int e = threadIdx.x + k * 256;
            float s1 = 0.f, s2 = 0.f;
            for (int d = 0; d < DEP; ++d) {
                float td = tl[d];
                s1 += td * W1[(HID + d) * DSZ + e];
                s2 += td * W2[(HID + d) * DSZ + e];
            }
            long i0 = (long)t * DSZ + e;
            unsigned short h2 = f2bf(s2), h1 = f2bf(s1);
            Ehi[i0] = h2;      Elo[i0] = f2bf(s2 - bf2f(h2));
            Ehi[EN + i0] = h1; Elo[EN + i0] = f2bf(s1 - bf2f(h1));
            dotacc += s1 * s2;
        }
        red[threadIdx.x] = dotacc;
        __syncthreads();
        for (int w = 128; w >= 1; w >>= 1) {
            if (threadIdx.x < w) red[threadIdx.x] += red[threadIdx.x + w];
            __syncthreads();
        }
        if (threadIdx.x == 0) cv[t] = red[0];
    }
}

// ---------------------------------------------------------------------------
// P stage direct: 128x64-tile split-precision GEMM, fused bias + hi/lo out.
// 2-phase double-buffered pipeline.  Grid (12, 8, 2) = 192 blocks.
__global__ __launch_bounds__(256) void pgemm_direct(
    const unsigned short* __restrict__ hHi, const unsigned short* __restrict__ hLo,
    const unsigned short* __restrict__ WtHi, const unsigned short* __restrict__ WtLo,
    const float* __restrict__ b1, const float* __restrict__ b2,
    unsigned short* __restrict__ Phi, unsigned short* __restrict__ Plo) {
    const long MN = (long)BB * SS * DSZ;
    const long WN = (long)DSZ * HID;
    int which = blockIdx.z;
    int m0 = blockIdx.y * 128, n0 = blockIdx.x * 64;
    const unsigned short* bh = WtHi + (long)which * WN;
    const unsigned short* bl = WtLo + (long)which * WN;
    const float* bias = which ? b2 : b1;
    unsigned short* oh = Phi + (long)which * MN;
    unsigned short* ol = Plo + (long)which * MN;

    __shared__ __align__(16) unsigned short sAh[8192], sAl[8192];
    __shared__ __align__(16) unsigned short sBh[4096], sBl[4096];
    int tid = threadIdx.x, lane = tid & 63, wave = tid >> 6;
    int wr = wave >> 1, wc = wave & 1;
    int q = lane >> 4, r = lane & 15;

    f32x4 acc[4][2];
#pragma unroll
    for (int i = 0; i < 4; ++i)
#pragma unroll
        for (int j = 0; j < 2; ++j) acc[i][j] = (f32x4){0.f, 0.f, 0.f, 0.f};

    int arow0 = tid >> 2, ak0 = (tid & 3) << 3;
    int s1 = tid + 256;
    int arow1 = s1 >> 2, ak1 = (s1 & 3) << 3;
    const unsigned short* aP0 = hHi + (long)(m0 + arow0) * HID + ak0;
    const unsigned short* aP1 = hHi + (long)(m0 + arow1) * HID + ak1;
    const unsigned short* alP0 = hLo + (long)(m0 + arow0) * HID + ak0;
    const unsigned short* alP1 = hLo + (long)(m0 + arow1) * HID + ak1;
    const unsigned short* bP  = bh + (long)(n0 + arow0) * DSZ + ak0;
    const unsigned short* blP = bl + (long)(n0 + arow0) * DSZ + ak0;

    int aOff[4], bOff[2];
#pragma unroll
    for (int f = 0; f < 4; ++f) aOff[f] = (wr * 64 + f * 16 + r) * 32 + q * 8;
#pragma unroll
    for (int f = 0; f < 2; ++f) bOff[f] = (wc * 32 + f * 16 + r) * 32 + q * 8;

    auto stage = [&](int k0, int db) {
        unsigned short* a = sAh + db * 4096;
        unsigned short* al_ = sAl + db * 4096;
        unsigned short* b = sBh + db * 2048;
        unsigned short* bl_ = sBl + db * 2048;
        gld16(aP0 + k0, a + (wave << 9));
        gld16(aP1 + k0, a + 2048 + (wave << 9));
        gld16(alP0 + k0, al_ + (wave << 9));
        gld16(alP1 + k0, al_ + 2048 + (wave << 9));
        gld16(bP + k0, b + (wave << 9));
        gld16(blP + k0, bl_ + (wave << 9));
    };

    stage(0, 0);
    __syncthreads();
    int db = 0;
    for (int k0 = 0; k0 < HID; k0 += 32) {
        if (k0 + 32 < HID) stage(k0 + 32, db ^ 1);
        const unsigned short* cAh = sAh + db * 4096;
        const unsigned short* cAl = sAl + db * 4096;
        const unsigned short* cBh = sBh + db * 2048;
        const unsigned short* cBl = sBl + db * 2048;
        bfv8 b0h = *(const bfv8*)(cBh + bOff[0]);
        bfv8 b1h = *(const bfv8*)(cBh + bOff[1]);
        bfv8 b0l = *(const bfv8*)(cBl + bOff[0]);
        bfv8 b1l = *(const bfv8*)(cBl + bOff[1]);
#pragma unroll
        for (int fr = 0; fr < 4; ++fr) {
            bfv8 a_h = *(const bfv8*)(cAh + aOff[fr]);
            bfv8 a_l = *(const bfv8*)(cAl + aOff[fr]);
            acc[fr][0] = __builtin_amdgcn_mfma_f32_16x16x32_bf16(a_h, b0h, acc[fr][0], 0, 0, 0);
            acc[fr][0] = __builtin_amdgcn_mfma_f32_16x16x32_bf16(a_h, b0l, acc[fr][0], 0, 0, 0);
            acc[fr][0] = __builtin_amdgcn_mfma_f32_16x16x32_bf16(a_l, b0h, acc[fr][0], 0, 0, 0);
            acc[fr][1] = __builtin_amdgcn_mfma_f32_16x16x32_bf16(a_h, b1h, acc[fr][1], 0, 0, 0);
            acc[fr][1] = __builtin_amdgcn_mfma_f32_16x16x32_bf16(a_h, b1l, acc[fr][1], 0, 0, 0);
            acc[fr][1] = __builtin_amdgcn_mfma_f32_16x16x32_bf16(a_l, b1h, acc[fr][1], 0, 0, 0);
        }
        __syncthreads();
        db ^= 1;
    }
#pragma unroll
    for (int fr = 0; fr < 4; ++fr) {
        int rr = m0 + wr * 64 + fr * 16 + q * 4;
#pragma unroll
        for (int fc = 0; fc < 2; ++fc) {
            int cc = n0 + wc * 32 + fc * 16 + r;
            float bv = bias[cc];
#pragma unroll
            for (int i = 0; i < 4; ++i) {
                float v = acc[fr][fc][i] + bv;
                unsigned short hh = f2bf(v);
                long o = (long)(rr + i) * DSZ + cc;
                oh[o] = hh;
                ol[o] = f2bf(v - bf2f(hh));
            }
        }
    }
}

// ---------------------------------------------------------------------------
// 128x128 split-precision MFMA core (triple MFMA), fp32 out to Cb.
// 2-phase double-buffered; smem = 32768 shorts.
__device__ __forceinline__ void mfma_core(
    const unsigned short* __restrict__ ah, const unsigned short* __restrict__ al,
    const unsigned short* __restrict__ bh, const unsigned short* __restrict__ bl,
    float* __restrict__ Cb, int K, int kb, int kend, int ldc, int Nvalid,
    int m0, int n0, unsigned short* smem) {
    unsigned short* sAh = smem;              // 2 x 4096
    unsigned short* sAl = smem + 8192;       // 2 x 4096
    unsigned short* sBh = smem + 16384;      // 2 x 4096
    unsigned short* sBl = smem + 24576;      // 2 x 4096
    int tid = threadIdx.x;
    int lane = tid & 63, wave = tid >> 6;
    int wr = wave >> 1, wc = wave & 1;
    int q = lane >> 4, r = lane & 15;

    f32x4 acc[4][4];
#pragma unroll
    for (int i = 0; i < 4; ++i)
#pragma unroll
        for (int j = 0; j < 4; ++j) acc[i][j] = (f32x4){0.f, 0.f, 0.f, 0.f};

    int s0 = tid, s1 = tid + 256;
    int arow0 = s0 >> 2, ak0 = (s0 & 3) << 3;
    int arow1 = s1 >> 2, ak1 = (s1 & 3) << 3;
    const unsigned short* aP0 = ah + (long)(m0 + arow0) * K + ak0;
    const unsigned short* aP1 = ah + (long)(m0 + arow1) * K + ak1;
    bool bok0 = (n0 + arow0) < Nvalid, bok1 = (n0 + arow1) < Nvalid;
    const unsigned short* bP0 = bh + (long)(n0 + arow0) * K + ak0;
    const unsigned short* bP1 = bh + (long)(n0 + arow1) * K + ak1;
    const unsigned short* alP0 = al + (long)(m0 + arow0) * K + ak0;
    const unsigned short* alP1 = al + (long)(m0 + arow1) * K + ak1;
    const unsigned short* blP0 = bl + (long)(n0 + arow0) * K + ak0;
    const unsigned short* blP1 = bl + (long)(n0 + arow1) * K + ak1;

    int aOff[4], bOff[4];
#pragma unroll
    for (int f = 0; f < 4; ++f) {
        aOff[f] = (wr * 64 + f * 16 + r) * 32 + q * 8;
        bOff[f] = (wc * 64 + f * 16 + r) * 32 + q * 8;
    }

    auto stage = [&](int k0, int db) {
        unsigned short* a = sAh + db * 4096;
        unsigned short* al_ = sAl + db * 4096;
        unsigned short* b = sBh + db * 4096;
        unsigned short* bl_ = sBl + db * 4096;
        gld16(aP0 + k0, a + (wave << 9));
        gld16(aP1 + k0, a + 2048 + (wave << 9));
        gld16(alP0 + k0, al_ + (wave << 9));
        gld16(alP1 + k0, al_ + 2048 + (wave << 9));
        if (bok0) gld16(bP0 + k0, b + (wave << 9));
        if (bok1) gld16(bP1 + k0, b + 2048 + (wave << 9));
        if (bok0) gld16(blP0 + k0, bl_ + (wave << 9));
        if (bok1) gld16(blP1 + k0, bl_ + 2048 + (wave << 9));
    };

    stage(kb, 0);
    __syncthreads();
    int db = 0;
    for (int k0 = kb; k0 < kend; k0 += 32) {
        if (k0 + 32 < kend) stage(k0 + 32, db ^ 1);
        const unsigned short* cAh = sAh + db * 4096;
        const unsigned short* cAl = sAl + db * 4096;
        const unsigned short* cBh = sBh + db * 4096;
        const unsigned short* cBl = sBl + db * 4096;
        bfv8 bh_r[4], bl_r[4];
#pragma unroll
        for (int fc = 0; fc < 4; ++fc) {
            bh_r[fc] = *(const bfv8*)(cBh + bOff[fc]);
            bl_r[fc] = *(const bfv8*)(cBl + bOff[fc]);
        }
#pragma unroll
        for (int fr = 0; fr < 4; ++fr) {
            bfv8 a_h = *(const bfv8*)(cAh + aOff[fr]);
            bfv8 a_l = *(const bfv8*)(cAl + aOff[fr]);
#pragma unroll
            for (int fc = 0; fc < 4; ++fc) {
                acc[fr][fc] = __builtin_amdgcn_mfma_f32_16x16x32_bf16(a_h, bh_r[fc], acc[fr][fc], 0, 0, 0);
                acc[fr][fc] = __builtin_amdgcn_mfma_f32_16x16x32_bf16(a_h, bl_r[fc], acc[fr][fc], 0, 0, 0);
                acc[fr][fc] = __builtin_amdgcn_mfma_f32_16x16x32_bf16(a_l, bh_r[fc], acc[fr][fc], 0, 0, 0);
            }
        }
        __syncthreads();
        db ^= 1;
    }
#pragma unroll
    for (int fr = 0; fr < 4; ++fr) {
        int rr = m0 + wr * 64 + fr * 16 + q * 4;
#pragma unroll
        for (int fc = 0; fc < 4; ++fc) {
            int cc = n0 + wc * 64 + fc * 16 + r;
            if (cc < Nvalid) {
#pragma unroll
                for (int i = 0; i < 4; ++i)
                    Cb[(long)(rr + i) * ldc + cc] = acc[fr][fc][i];
            }
        }
    }
}

// ---------------------------------------------------------------------------
// UV (0..95, split 6) + Gram (96..191, split 12) + HG (192..383). Grid (384).
__global__ __launch_bounds__(256) void uvgram_hg(
    const unsigned short* __restrict__ Phi, const unsigned short* __restrict__ Plo,
    const unsigned short* __restrict__ EtHi, const unsigned short* __restrict__ EtLo,
    float* __restrict__ UVP, float* __restrict__ GP,
    const unsigned short* __restrict__ hHi, const unsigned short* __restrict__ gTHi,
    unsigned short* __restrict__ HGT) {
    const long MN = (long)BB * SS * DSZ;
    const long EN = (long)NTP * DSZ;
    const long UVN = (long)BB * SS * NTP;
    const long BSD = (long)SS * DSZ;
    __shared__ __align__(16) unsigned short smem[32768];
    int id = blockIdx.x;
    if (id < 96) {
        // UV: y = id/12, z = id%12, which = z/6, split = z%6 (K-chunk 128)
        int y = id / 12, z = id % 12;
        int which = z / 6, split = z % 6;
        mfma_core(Phi + (long)which * MN, Plo + (long)which * MN,
                  EtHi + (long)which * EN, EtLo + (long)which * EN,
                  UVP + ((long)which * 6 + split) * UVN,
                  DSZ, split * 128, split * 128 + 128, NTP, NTP,
                  y * 128, 0, smem);
    } else if (id < 192) {
        // Gram: g = id-96, b = g/12, split = g%12 (K-chunk 64)
        int g = id - 96;
        int b = g / 12, split = g % 12;
        mfma_core(Phi + (long)b * BSD, Plo + (long)b * BSD,
                  Phi + MN + (long)b * BSD, Plo + MN + (long)b * BSD,
                  GP + ((long)b * 12 + split) * (SS * SS),
                  DSZ, split * 64, split * 64 + 64, SS, SS,
                  0, 0, smem);
    } else {
        // HG^T = (h @ gcn)^T per batch: 64x64-tile hi-only GEMM, K=768.
        int hgid = id - 192;                 // 0..191
        int n0 = (hgid % 12) * 64, m0 = (hgid / 12) * 64;
        unsigned short* sA = smem;           // 2 x 2048
        unsigned short* sB = smem + 4096;    // 2 x 2048
        int tid = threadIdx.x, lane = tid & 63, wave = tid >> 6;
        int wr = wave >> 1, wc = wave & 1;
        int q = lane >> 4, r = lane & 15;
        f32x4 acc[2][2];
#pragma unroll
        for (int i = 0; i < 2; ++i)
#pragma unroll
            for (int j = 0; j < 2; ++j) acc[i][j] = (f32x4){0.f, 0.f, 0.f, 0.f};
        int arow = tid >> 2, ak = (tid & 3) << 3;
        const unsigned short* aP = hHi + (long)(m0 + arow) * HID + ak;
        const unsigned short* bP = gTHi + (long)(n0 + arow) * HID + ak;
        int aOff[2], bOff[2];
#pragma unroll
        for (int f = 0; f < 2; ++f) {
            aOff[f] = (wr * 32 + f * 16 + r) * 32 + q * 8;
            bOff[f] = (wc * 32 + f * 16 + r) * 32 + q * 8;
        }
        auto stage = [&](int k0, int db) {
            gld16(aP + k0, sA + db * 2048 + (wave << 9));
            gld16(bP + k0, sB + db * 2048 + (wave << 9));
        };
        stage(0, 0);
        __syncthreads();
        int db = 0;
        for (int k0 = 0; k0 < HID; k0 += 32) {
            if (k0 + 32 < HID) stage(k0 + 32, db ^ 1);
            const unsigned short* cA = sA + db * 2048;
            const unsigned short* cB = sB + db * 2048;
            bfv8 b0 = *(const bfv8*)(cB + bOff[0]);
            bfv8 b1 = *(const bfv8*)(cB + bOff[1]);
#pragma unroll
            for (int fr = 0; fr < 2; ++fr) {
                bfv8 a = *(const bfv8*)(cA + aOff[fr]);
                acc[fr][0] = __builtin_amdgcn_mfma_f32_16x16x32_bf16(a, b0, acc[fr][0], 0, 0, 0);
                acc[fr][1] = __builtin_amdgcn_mfma_f32_16x16x32_bf16(a, b1, acc[fr][1], 0, 0, 0);
            }
            __syncthreads();
            db ^= 1;
        }
#pragma unroll
        for (int fr = 0; fr < 2; ++fr) {
            int rr = m0 + wr * 32 + fr * 16 + q * 4;
#pragma unroll
            for (int fc = 0; fc < 2; ++fc) {
                int cc = n0 + wc * 32 + fc * 16 + r;
#pragma unroll
                for (int i = 0; i < 4; ++i) {
                    int m = rr + i;
                    long o = (long)(m >> 7) * ((long)HID * SS) + (long)cc * SS + (m & 127);
                    HGT[o] = f2bf(acc[fr][fc][i]);
                }
            }
        }
    }
}

// ---------------------------------------------------------------------------
// 64x64-tile bf16 GEMM (hi-only), 2-phase pipelined, fused epilogue.
// OUT==1: bf16 out (+bias)(+relu).  OUT==2: fp32 out (+bias).
template <int OUT>
__global__ __launch_bounds__(256) void gemm64(
    const unsigned short* __restrict__ Ahi, const unsigned short* __restrict__ Bhi,
    const float* __restrict__ bias, unsigned short* __restrict__ Chi,
    float* __restrict__ Cf, int relu, int K, int ldc,
    long sA, long sB, long sC) {
    int batch = blockIdx.z;
    int m0 = blockIdx.y * 64, n0 = blockIdx.x * 64;
    const unsigned short* ah = Ahi + (long)batch * sA;
    const unsigned short* bh = Bhi + (long)batch * sB;

    __shared__ __align__(16) unsigned short sAh[4096], sBh[4096];
    int tid = threadIdx.x;
    int lane = tid & 63, wave = tid >> 6;
    int wr = wave >> 1, wc = wave & 1;
    int q = lane >> 4, r = lane & 15;

    f32x4 acc[2][2];
#pragma unroll
    for (int i = 0; i < 2; ++i)
#pragma unroll
        for (int j = 0; j < 2; ++j) acc[i][j] = (f32x4){0.f, 0.f, 0.f, 0.f};

    int arow = tid >> 2, ak = (tid & 3) << 3;
    const unsigned short* aP = ah + (long)(m0 + arow) * K + ak;
    const unsigned short* bP = bh + (long)(n0 + arow) * K + ak;

    int aOff[2], bOff[2];
#pragma unroll
    for (int f = 0; f < 2; ++f) {
        aOff[f] = (wr * 32 + f * 16 + r) * 32 + q * 8;
        bOff[f] = (wc * 32 + f * 16 + r) * 32 + q * 8;
    }

    auto stage = [&](int k0, int db) {
        gld16(aP + k0, sAh + db * 2048 + (wave << 9));
        gld16(bP + k0, sBh + db * 2048 + (wave << 9));
    };
    stage(0, 0);
    __syncthreads();
    int db = 0;
    for (int k0 = 0; k0 < K; k0 += 32) {
        if (k0 + 32 < K) stage(k0 + 32, db ^ 1);
        const unsigned short* cA = sAh + db * 2048;
        const unsigned short* cB = sBh + db * 2048;
        bfv8 b0 = *(const bfv8*)(cB + bOff[0]);
        bfv8 b1 = *(const bfv8*)(cB + bOff[1]);
#pragma unroll
        for (int fr = 0; fr < 2; ++fr) {
            bfv8 a = *(const bfv8*)(cA + aOff[fr]);
            acc[fr][0] = __builtin_amdgcn_mfma_f32_16x16x32_bf16(a, b0, acc[fr][0], 0, 0, 0);
            acc[fr][1] = __builtin_amdgcn_mfma_f32_16x16x32_bf16(a, b1, acc[fr][1], 0, 0, 0);
        }
        __syncthreads();
        db ^= 1;
    }
#pragma unroll
    for (int fr = 0; fr < 2; ++fr) {
        int rr = m0 + wr * 32 + fr * 16 + q * 4;
#pragma unroll
        for (int fc = 0; fc < 2; ++fc) {
            int cc = n0 + wc * 32 + fc * 16 + r;
            float bv = bias ? bias[cc] : 0.f;
#pragma unroll
            for (int i = 0; i < 4; ++i) {
                float v = acc[fr][fc][i] + bv;
                if constexpr (OUT == 1) {
                    if (relu) v = fmaxf(v, 0.f);
                    Chi[(long)batch * sC + (long)(rr + i) * ldc + cc] = f2bf(v);
                } else {
                    Cf[(long)batch * sC + (long)(rr + i) * ldc + cc] = v;
                }
            }
        }
    }
}

// ---------------------------------------------------------------------------
// relevance (sum 12 Gram partials + 6 UV partials + c) + mask + softmax.
__global__ __launch_bounds__(128) void softmax_kernel(
    const int* __restrict__ dep, const float* __restrict__ Gp,
    const float* __restrict__ Up, const float* __restrict__ cv,
    unsigned short* __restrict__ Ahi) {
    const long UVN = (long)BB * SS * NTP;
    int bi = blockIdx.x;
    int b = bi >> 7;
    int j = threadIdx.x;
    int t = dep[(long)bi * SS + j];
    float r;
    if (t != 0) {
        long gbase = (long)bi * SS + j + (long)b * 11L * SS * SS;
        float g = 0.f;
        for (int s = 0; s < 12; ++s) g += Gp[gbase + (long)s * (SS * SS)];
        float su = 0.f, sv = 0.f;
        long ui = (long)bi * NTP + t;
        long vi = ((long)b * SS + j) * NTP + t;
        for (int s = 0; s < 6; ++s) {
            su += Up[(long)s * UVN + ui];
            sv += Up[(long)(6 + s) * UVN + vi];
        }
        r = g + su + sv + cv[t];
    } else {
        r = NEG;
    }
    float m = r;
    for (int off = 1; off < 64; off <<= 1) m = fmaxf(m, __shfl_xor(m, off));
    __shared__ float smax[2], ssum[2];
    if ((threadIdx.x & 63) == 0) smax[threadIdx.x >> 6] = m;
    __syncthreads();
    m = fmaxf(smax[0], smax[1]);
    float p = expf(r - m);
    float s = p;
    for (int off = 1; off < 64; off <<= 1) s += __shfl_xor(s, off);
    if ((threadIdx.x & 63) == 0) ssum[threadIdx.x >> 6] = s;
    __syncthreads();
    s = ssum[0] + ssum[1];
    Ahi[(long)bi * SS + j] = f2bf(p / s);
}

// ===========================================================================
// Legacy fp32 path (ws-size fallback) — verified in rounds 1-3.
__global__ void e_kernel(const float* __restrict__ table,
                         const float* __restrict__ W1,
                         const float* __restrict__ W2,
                         float* __restrict__ Ef) {
    int idx = blockIdx.x * blockDim.x + threadIdx.x;
    if (idx >= NTP * DSZ) return;
    int t = idx / DSZ, e = idx % DSZ;
    float s1 = 0.f, s2 = 0.f;
    if (t < NT)
        for (int d = 0; d < DEP; ++d) {
            float td = table[t * DEP + d];
            s1 += td * W1[(HID + d) * DSZ + e];
            s2 += td * W2[(HID + d) * DSZ + e];
        }
    const long EN = (long)NTP * DSZ;
    Ef[idx] = s2; Ef[EN + idx] = s1;
}

__global__ void c_kernel(const float* __restrict__ Ef, float* __restrict__ cv) {
    int t = blockIdx.x;
    const long EN = (long)NTP * DSZ;
    float s = 0.f;
    for (int e = threadIdx.x; e < DSZ; e += 256)
        s += Ef[(long)t * DSZ + e] * Ef[EN + (long)t * DSZ + e];
    __shared__ float red[256];
    red[threadIdx.x] = s;
    __syncthreads();
    for (int w = 128; w >= 1; w >>= 1) {
        if (threadIdx.x < w) red[threadIdx.x] += red[threadIdx.x + w];
        __syncthreads();
    }
    if (threadIdx.x == 0) cv[t] = red[0];
}

__device__ __forceinline__ void gemm_body(
    const float* __restrict__ Ab, const float* __restrict__ Bb,
    const float* __restrict__ bias, float* __restrict__ Cb,
    int kbeg, int kend, int lda, int ldb, int ldc,
    int row0, int col0, bool relu) {
    __shared__ float As[16][68];
    __shared__ float Bs[16][68];
    int tx = threadIdx.x & 15, ty = threadIdx.x >> 4;
    float acc[4][4] = {};
    for (int k0 = kbeg; k0 < kend; k0 += 16) {
#pragma unroll
        for (int l = 0; l < 4; ++l) {
            int idx = threadIdx.x + l * 256;
            int r = idx >> 4, kk = idx & 15;
            As[kk][r] = Ab[(long)(row0 + r) * lda + k0 + kk];
            int kk2 = idx >> 6, cc = idx & 63;
            Bs[kk2][cc] = Bb[(long)(k0 + kk2) * ldb + col0 + cc];
        }
        __syncthreads();
#pragma unroll
        for (int kk = 0; kk < 16; ++kk) {
            float4 a4 = *(const float4*)&As[kk][ty * 4];
            float4 b4 = *(const float4*)&Bs[kk][tx * 4];
            float a[4] = {a4.x, a4.y, a4.z, a4.w};
            float b[4] = {b4.x, b4.y, b4.z, b4.w};
#pragma unroll
            for (int i = 0; i < 4; ++i)
#pragma unroll
                for (int j = 0; j < 4; ++j) acc[i][j] += a[i] * b[j];
        }
        __syncthreads();
    }
#pragma unroll
    for (int i = 0; i < 4; ++i) {
        int r = row0 + ty * 4 + i;
#pragma unroll
        for (int j = 0; j < 4; ++j) {
            int c = col0 + tx * 4 + j;
            float v = acc[i][j];
            if (bias) v += bias[c];
            if (relu) v = fmaxf(v, 0.f);
            Cb[(long)r * ldc + c] = v;
        }
    }
}

__global__ __launch_bounds__(256) void gemm_k(
    const float* __restrict__ A, const float* __restrict__ B,
    const float* __restrict__ bias, float* __restrict__ C,
    int K, int nsplit, int lda, int ldb, int ldc,
    long sA, long sB, long sC, long splitStride, int relu) {
    int batch = blockIdx.z / nsplit, split = blockIdx.z % nsplit;
    int kc = K / nsplit;
    const float* Ab = A + (long)batch * sA;
    const float* Bb = B + (long)batch * sB;
    float* Cb = C + (long)batch * sC + (long)split * splitStride;
    gemm_body(Ab, Bb, nsplit == 1 ? bias : nullptr, Cb,
              split * kc, split * kc + kc, lda, ldb, ldc,
              blockIdx.y * 64, blockIdx.x * 64, relu && nsplit == 1);
}

__global__ __launch_bounds__(256) void gram32(
    const float* __restrict__ P1, const float* __restrict__ P2,
    float* __restrict__ Gp) {
    int b = blockIdx.z;
    int i0 = blockIdx.y * 32, j0 = blockIdx.x * 32;
    __shared__ float As[32][33];
    __shared__ float Bs[32][33];
    const float* p1 = P1 + (long)b * SS * DSZ;
    const float* p2 = P2 + (long)b * SS * DSZ;
    int tx = threadIdx.x % 32, ty = threadIdx.x / 32;
    float acc[4] = {0.f, 0.f, 0.f, 0.f};
    for (int k0 = 0; k0 < DSZ; k0 += 32) {
#pragma unroll
        for (int l = 0; l < 4; ++l) {
            int idx = threadIdx.x + l * 256;
            int r = idx / 32, kk = idx % 32;
            As[kk][r] = p1[(long)(i0 + r) * DSZ + k0 + kk];
            Bs[kk][r] = p2[(long)(j0 + r) * DSZ + k0 + kk];
        }
        __syncthreads();
#pragma unroll
        for (int kk = 0; kk < 32; ++kk) {
            float bv = Bs[kk][tx];
#pragma unroll
            for (int i = 0; i < 4; ++i) acc[i] += As[kk][ty * 4 + i] * bv;
        }
        __syncthreads();
    }
#pragma unroll
    for (int i = 0; i < 4; ++i)
        Gp[((long)b * SS + i0 + ty * 4 + i) * SS + j0 + tx] = acc[i];
}

__global__ __launch_bounds__(256) void uv_kernel(
    const float* __restrict__ P1, const float* __restrict__ P2,
    const float* __restrict__ E1, const float* __restrict__ E2,
    const float* __restrict__ cv, float* __restrict__ U, float* __restrict__ V) {
    int bs = blockIdx.x;
    __shared__ float p1[DSZ], p2[DSZ];
    for (int e = threadIdx.x; e < DSZ; e += 256) {
        p1[e] = P1[(long)bs * DSZ + e];
        p2[e] = P2[(long)bs * DSZ + e];
    }
    __syncthreads();
    int wave = threadIdx.x / 64, lane = threadIdx.x % 64;
    for (int t = wave; t < NT; t += 4) {
        float su = 0.f, sv = 0.f;
        for (int e = lane; e < DSZ; e += 64) {
            su += p1[e] * E2[(long)t * DSZ + e];
            sv += p2[e] * E1[(long)t * DSZ + e];
        }
        for (int off = 32; off >= 1; off >>= 1) {
            su += __shfl_down(su, off);
            sv += __shfl_down(sv, off);
        }
        if (lane == 0) {
            U[(long)bs * NTP + t] = su;
            V[(long)bs * NTP + t] = sv + cv[t];
        }
    }
}

__global__ __launch_bounds__(128) void softmax_fb(
    const int* __restrict__ dep, const float* __restrict__ G,
    const float* __restrict__ U, const float* __restrict__ V,
    float* __restrict__ A) {
    int bi = blockIdx.x;
    int b = bi >> 7;
    int j = threadIdx.x;
    int t = dep[(long)bi * SS + j];
    float r;
    if (t != 0)
        r = G[(long)bi * SS + j] + U[(long)bi * NTP + t] + V[((long)b * SS + j) * NTP + t];
    else
        r = NEG;
    float m = r;
    for (int off = 1; off < 64; off <<= 1) m = fmaxf(m, __shfl_xor(m, off));
    __shared__ float smax[2], ssum[2];
    if ((threadIdx.x & 63) == 0) smax[threadIdx.x >> 6] = m;
    __syncthreads();
    m = fmaxf(smax[0], smax[1]);
    float p = expf(r - m);
    float s = p;
    for (int off = 1; off < 64; off <<= 1) s += __shfl_xor(s, off);
    if ((threadIdx.x & 63) == 0) ssum[threadIdx.x >> 6] = s;
    __syncthreads();
    s = ssum[0] + ssum[1];
    A[(long)bi * SS + j] = p / s;
}

// ---------------------------------------------------------------------------
extern "C" void kernel_launch(void* const* d_in, const int* in_sizes, int n_in,
                              void* d_out, int out_size, void* d_ws, size_t ws_size,
                              hipStream_t stream) {
    const float* h      = (const float*)d_in[0];
    const int*   dep    = (const int*)d_in[1];
    const float* table  = (const float*)d_in[2];
    const float* W1_w   = (const float*)d_in[3];
    const float* W1_b   = (const float*)d_in[4];
    const float* W2_w   = (const float*)d_in[5];
    const float* W2_b   = (const float*)d_in[6];
    const float* gcn_w  = (const float*)d_in[7];
    const float* gcn_b  = (const float*)d_in[8];
    const float* Wo_w   = (const float*)d_in[9];
    const float* Wo_b   = (const float*)d_in[10];
    float* out = (float*)d_out;

    const long nBS = (long)BB * SS;        // 1024
    const long MN  = nBS * DSZ;            // 786432
    const long BSS = (long)BB * SS * SS;   // 131072
    const long UVN = nBS * NTP;            // 49152
    const long EN  = (long)NTP * DSZ;      // 36864
    const long WN  = (long)DSZ * HID;      // 589824
    const long BSD = (long)SS * DSZ;       // 98304

    char* base = (char*)d_ws;
    size_t off = 0;
    auto alloc = [&](size_t bytes) -> void* {
        void* p = base + off;
        off += (bytes + 255) & ~(size_t)255;
        return p;
    };

    float* CV    = (float*)alloc(256);
    float* GP    = (float*)alloc(12 * BSS * 4);   // Gram partials (12 splits)
    float* UVP   = (float*)alloc(12 * UVN * 4);   // UV partials (2 x 6 splits)
    unsigned short* EtHi = (unsigned short*)alloc(2 * EN * 2);
    unsigned short* EtLo = (unsigned short*)alloc(2 * EN * 2);
    unsigned short* hHi  = (unsigned short*)alloc(MN * 2);
    unsigned short* hLo  = (unsigned short*)alloc(MN * 2);
    unsigned short* WtHi = (unsigned short*)alloc(2 * WN * 2);
    unsigned short* WtLo = (unsigned short*)alloc(2 * WN * 2);
    unsigned short* gTHi = (unsigned short*)alloc(WN * 2);
    unsigned short* oTHi = (unsigned short*)alloc(WN * 2);
    unsigned short* Phi  = (unsigned short*)alloc(2 * MN * 2);
    unsigned short* Plo  = (unsigned short*)alloc(2 * MN * 2);
    unsigned short* AmHi = (unsigned short*)alloc(BSS * 2);
    unsigned short* HGT  = (unsigned short*)alloc(MN * 2);   // [8][768][128]
    unsigned short* HSHi = (unsigned short*)alloc(MN * 2);
    size_t needBig = off;

    if (ws_size >= needBig) {
        // 1. conversions + E + c  (one launch, vectorized)
        convec<<<dim3(24, 24, 13), 256, 0, stream>>>(
            h, table, W1_w, W2_w, gcn_w, Wo_w,
            hHi, hLo, WtHi, WtLo, gTHi, oTHi, EtHi, EtLo, CV);
        // 2. P1/P2 direct: 128x64-tile pipelined, fused bias + hi/lo, 192 blk
        pgemm_direct<<<dim3(12, 8, 2), 256, 0, stream>>>(
            hHi, hLo, WtHi, WtLo, W1_b, W2_b, Phi, Plo);
        // 3. UV + Gram + HG fused (96 + 96 + 192 = 384 blocks)
        uvgram_hg<<<384, 256, 0, stream>>>(
            Phi, Plo, EtHi, EtLo, UVP, GP, hHi, gTHi, HGT);
        // 4. softmax -> bf16 A
        softmax_kernel<<<nBS, 128, 0, stream>>>(dep, GP, UVP, CV, AmHi);
        // 5. HSYN = relu(A @ HG^T + gcn_b): batched K=128 -> 192 blk
        gemm64<1><<<dim3(12, 2, 8), 256, 0, stream>>>(
            AmHi, HGT, gcn_b, HSHi, nullptr, 1, SS, HID,
            (long)SS * SS, (long)HID * SS, BSD);
        // 6. out = HSYN @ Wo + b -> 192 blk, fp32 direct
        gemm64<2><<<dim3(12, 16, 1), 256, 0, stream>>>(
            HSHi, oTHi, Wo_b, nullptr, out, 0, DSZ, HID, 0, 0, 0);
    } else {
        // Fallback: verified fp32 nsplit=1 path, compact layout.
        float* ws = (float*)d_ws;
        long o2 = 0;
        float* Ef2  = ws + o2; o2 += 2 * EN;
        float* CV2  = ws + o2; o2 += 64;
        float* P1   = ws + o2; o2 += MN;
        float* P2   = ws + o2; o2 += MN;
        float* Uf   = ws + o2; o2 += UVN;
        float* Vf   = ws + o2; o2 += UVN;
        float* G    = ws + o2; o2 += BSS;
        float* Amat = ws + o2; o2 += BSS;
        float* AGG  = ws + o2; o2 += MN;
        float* HSYN = ws + o2; o2 += MN;

        e_kernel<<<(NTP * DSZ + 255) / 256, 256, 0, stream>>>(table, W1_w, W2_w, Ef2);
        c_kernel<<<NT, 256, 0, stream>>>(Ef2, CV2);
        gemm_k<<<dim3(DSZ / 64, nBS / 64, 1), 256, 0, stream>>>(
            h, W1_w, W1_b, P1, HID, 1, HID, DSZ, DSZ, 0, 0, 0, 0, 0);
        gemm_k<<<dim3(DSZ / 64, nBS / 64, 1), 256, 0, stream>>>(
            h, W2_w, W2_b, P2, HID, 1, HID, DSZ, DSZ, 0, 0, 0, 0, 0);
        uv_kernel<<<nBS, 256, 0, stream>>>(P1, P2, Ef2 + EN, Ef2, CV2, Uf, Vf);
        gram32<<<dim3(SS / 32, SS / 32, BB), 256, 0, stream>>>(P1, P2, G);
        softmax_fb<<<nBS, 128, 0, stream>>>(dep, G, Uf, Vf, Amat);
        gemm_k<<<dim3(HID / 64, SS / 64, BB), 256, 0, stream>>>(
            Amat, h, nullptr, AGG, SS, 1, SS, HID, HID,
            (long)SS * SS, BSD, BSD, 0, 0);
        gemm_k<<<dim3(HID / 64, nBS / 64, 1), 256, 0, stream>>>(
            AGG, gcn_w, gcn_b, HSYN, HID, 1, HID, HID, HID, 0, 0, 0, 0, 1);
        gemm_k<<<dim3(HID / 64, nBS / 64, 1), 256, 0, stream>>>(
            HSYN, Wo_w, Wo_b, out, DSZ, 1, DSZ, HID, HID, 0, 0, 0, 0, 0);
    }
}

// Round 16
// 70.309 us; speedup vs baseline: 1.0773x; 1.0773x over previous
//
#include <hip/hip_runtime.h>
#include <hip/hip_bf16.h>

#define BB 8
#define SS 128
#define HID 768
#define DEP 64
#define DSZ 768
#define NT 45
#define NTP 48
#define NEG -1000000000.0f

typedef short bfv8 __attribute__((ext_vector_type(8)));
typedef float f32x4 __attribute__((ext_vector_type(4)));

__device__ __forceinline__ unsigned short f2bf(float x) {
    unsigned int u; __builtin_memcpy(&u, &x, 4);
    u += 0x7fffu + ((u >> 16) & 1u);
    return (unsigned short)(u >> 16);
}
__device__ __forceinline__ float bf2f(unsigned short h) {
    unsigned int u = ((unsigned int)h) << 16;
    float f; __builtin_memcpy(&f, &u, 4);
    return f;
}

// async global->LDS, 16B per lane; LDS dest is wave-uniform base.
__device__ __forceinline__ void gld16(const unsigned short* gp, unsigned short* lp) {
    typedef __attribute__((address_space(1))) const unsigned int GU;
    typedef __attribute__((address_space(3))) unsigned int LU;
    __builtin_amdgcn_global_load_lds((GU*)(uintptr_t)gp,
                                     (LU*)(unsigned int)(uintptr_t)lp, 16, 0, 0);
}

// ---------------------------------------------------------------------------
// convec: conversions + E/c, one launch. Grid (24, 24, 13).
__global__ __launch_bounds__(256) void convec(
    const float* __restrict__ h, const float* __restrict__ table,
    const float* __restrict__ W1, const float* __restrict__ W2,
    const float* __restrict__ gcn, const float* __restrict__ Wo,
    unsigned short* __restrict__ hHi, unsigned short* __restrict__ hLo,
    unsigned short* __restrict__ WtHi, unsigned short* __restrict__ WtLo,
    unsigned short* __restrict__ gTHi, unsigned short* __restrict__ oTHi,
    unsigned short* __restrict__ Ehi, unsigned short* __restrict__ Elo,
    float* __restrict__ cv) {
    const long WN = (long)DSZ * HID;
    int tr = threadIdx.x >> 5, tc = threadIdx.x & 31;
    int z = blockIdx.z;
    if (z < 4) {
        __shared__ float tile[32][33];
        const float* src = z == 0 ? W1 : z == 1 ? W2 : z == 2 ? gcn : Wo;
        unsigned short* dhi = z == 0 ? WtHi : z == 1 ? WtHi + WN
                            : z == 2 ? gTHi : oTHi;
        unsigned short* dlo = z == 0 ? WtLo : z == 1 ? WtLo + WN : nullptr;
        int r0 = blockIdx.y * 32, c0 = blockIdx.x * 32;
#pragma unroll
        for (int k = 0; k < 4; ++k)
            tile[tr + k * 8][tc] = src[(long)(r0 + tr + k * 8) * 768 + c0 + tc];
        __syncthreads();
#pragma unroll
        for (int k = 0; k < 4; ++k) {
            int i = tr + k * 8, j = tc;
            float v = tile[j][i];
            unsigned short hh = f2bf(v);
            long o = (long)(c0 + i) * 768 + r0 + j;
            dhi[o] = hh;
            if (dlo) dlo[o] = f2bf(v - bf2f(hh));
        }
    } else if (z < 12) {
        if (blockIdx.y >= SS / 32) return;
        int b = z - 4;
        int r0 = blockIdx.y * 32, c0 = blockIdx.x * 32;
        const float* Xb = h + (long)b * SS * HID;
#pragma unroll
        for (int k = 0; k < 4; ++k) {
            int rr = r0 + tr + k * 8, cc = c0 + tc;
            float v = Xb[(long)rr * HID + cc];
            unsigned short hh = f2bf(v);
            long o = (long)b * SS * HID + (long)rr * HID + cc;
            hHi[o] = hh;
            hLo[o] = f2bf(v - bf2f(hh));
        }
    } else {
        if (blockIdx.y >= 2) return;
        int t = blockIdx.y * 24 + blockIdx.x;
        if (t >= NT) return;
        const long EN = (long)NTP * DSZ;
        __shared__ float tl[DEP];
        __shared__ float red[256];
        for (int d = threadIdx.x; d < DEP; d += 256) tl[d] = table[t * DEP + d];
        __syncthreads();
        float dotacc = 0.f;
#pragma unroll
        for (int k = 0; k < 3; ++k) {
            int e = threadIdx.x + k * 256;
            float s1 = 0.f, s2 = 0.f;
            for (int d = 0; d < DEP; ++d) {
                float td = tl[d];
                s1 += td * W1[(HID + d) * DSZ + e];
                s2 += td * W2[(HID + d) * DSZ + e];
            }
            long i0 = (long)t * DSZ + e;
            unsigned short h2 = f2bf(s2), h1 = f2bf(s1);
            Ehi[i0] = h2;      Elo[i0] = f2bf(s2 - bf2f(h2));
            Ehi[EN + i0] = h1; Elo[EN + i0] = f2bf(s1 - bf2f(h1));
            dotacc += s1 * s2;
        }
        red[threadIdx.x] = dotacc;
        __syncthreads();
        for (int w = 128; w >= 1; w >>= 1) {
            if (threadIdx.x < w) red[threadIdx.x] += red[threadIdx.x + w];
            __syncthreads();
        }
        if (threadIdx.x == 0) cv[t] = red[0];
    }
}

// ---------------------------------------------------------------------------
// P body: 128x64-tile split-precision GEMM, 2-phase double-buffered,
// fused bias + hi/lo out.  Needs smem of 24576 shorts.
__device__ __forceinline__ void pgemm_body(
    const unsigned short* __restrict__ hHi, const unsigned short* __restrict__ hLo,
    const unsigned short* __restrict__ WtHi, const unsigned short* __restrict__ WtLo,
    const float* __restrict__ b1, const float* __restrict__ b2,
    unsigned short* __restrict__ Phi, unsigned short* __restrict__ Plo,
    int which, int m0, int n0, unsigned short* smem) {
    const long MN = (long)BB * SS * DSZ;
    const long WN = (long)DSZ * HID;
    const unsigned short* bh = WtHi + (long)which * WN;
    const unsigned short* bl = WtLo + (long)which * WN;
    const float* bias = which ? b2 : b1;
    unsigned short* oh = Phi + (long)which * MN;
    unsigned short* ol = Plo + (long)which * MN;

    unsigned short* sAh = smem;            // 2 x 4096
    unsigned short* sAl = smem + 8192;     // 2 x 4096
    unsigned short* sBh = smem + 16384;    // 2 x 2048
    unsigned short* sBl = smem + 20480;    // 2 x 2048
    int tid = threadIdx.x, lane = tid & 63, wave = tid >> 6;
    int wr = wave >> 1, wc = wave & 1;
    int q = lane >> 4, r = lane & 15;

    f32x4 acc[4][2];
#pragma unroll
    for (int i = 0; i < 4; ++i)
#pragma unroll
        for (int j = 0; j < 2; ++j) acc[i][j] = (f32x4){0.f, 0.f, 0.f, 0.f};

    int arow0 = tid >> 2, ak0 = (tid & 3) << 3;
    int s1 = tid + 256;
    int arow1 = s1 >> 2, ak1 = (s1 & 3) << 3;
    const unsigned short* aP0 = hHi + (long)(m0 + arow0) * HID + ak0;
    const unsigned short* aP1 = hHi + (long)(m0 + arow1) * HID + ak1;
    const unsigned short* alP0 = hLo + (long)(m0 + arow0) * HID + ak0;
    const unsigned short* alP1 = hLo + (long)(m0 + arow1) * HID + ak1;
    const unsigned short* bP  = bh + (long)(n0 + arow0) * DSZ + ak0;
    const unsigned short* blP = bl + (long)(n0 + arow0) * DSZ + ak0;

    int aOff[4], bOff[2];
#pragma unroll
    for (int f = 0; f < 4; ++f) aOff[f] = (wr * 64 + f * 16 + r) * 32 + q * 8;
#pragma unroll
    for (int f = 0; f < 2; ++f) bOff[f] = (wc * 32 + f * 16 + r) * 32 + q * 8;

    auto stage = [&](int k0, int db) {
        unsigned short* a = sAh + db * 4096;
        unsigned short* al_ = sAl + db * 4096;
        unsigned short* b = sBh + db * 2048;
        unsigned short* bl_ = sBl + db * 2048;
        gld16(aP0 + k0, a + (wave << 9));
        gld16(aP1 + k0, a + 2048 + (wave << 9));
        gld16(alP0 + k0, al_ + (wave << 9));
        gld16(alP1 + k0, al_ + 2048 + (wave << 9));
        gld16(bP + k0, b + (wave << 9));
        gld16(blP + k0, bl_ + (wave << 9));
    };

    stage(0, 0);
    __syncthreads();
    int db = 0;
    for (int k0 = 0; k0 < HID; k0 += 32) {
        if (k0 + 32 < HID) stage(k0 + 32, db ^ 1);
        const unsigned short* cAh = sAh + db * 4096;
        const unsigned short* cAl = sAl + db * 4096;
        const unsigned short* cBh = sBh + db * 2048;
        const unsigned short* cBl = sBl + db * 2048;
        bfv8 b0h = *(const bfv8*)(cBh + bOff[0]);
        bfv8 b1h = *(const bfv8*)(cBh + bOff[1]);
        bfv8 b0l = *(const bfv8*)(cBl + bOff[0]);
        bfv8 b1l = *(const bfv8*)(cBl + bOff[1]);
#pragma unroll
        for (int fr = 0; fr < 4; ++fr) {
            bfv8 a_h = *(const bfv8*)(cAh + aOff[fr]);
            bfv8 a_l = *(const bfv8*)(cAl + aOff[fr]);
            acc[fr][0] = __builtin_amdgcn_mfma_f32_16x16x32_bf16(a_h, b0h, acc[fr][0], 0, 0, 0);
            acc[fr][0] = __builtin_amdgcn_mfma_f32_16x16x32_bf16(a_h, b0l, acc[fr][0], 0, 0, 0);
            acc[fr][0] = __builtin_amdgcn_mfma_f32_16x16x32_bf16(a_l, b0h, acc[fr][0], 0, 0, 0);
            acc[fr][1] = __builtin_amdgcn_mfma_f32_16x16x32_bf16(a_h, b1h, acc[fr][1], 0, 0, 0);
            acc[fr][1] = __builtin_amdgcn_mfma_f32_16x16x32_bf16(a_h, b1l, acc[fr][1], 0, 0, 0);
            acc[fr][1] = __builtin_amdgcn_mfma_f32_16x16x32_bf16(a_l, b1h, acc[fr][1], 0, 0, 0);
        }
        __syncthreads();
        db ^= 1;
    }
#pragma unroll
    for (int fr = 0; fr < 4; ++fr) {
        int rr = m0 + wr * 64 + fr * 16 + q * 4;
#pragma unroll
        for (int fc = 0; fc < 2; ++fc) {
            int cc = n0 + wc * 32 + fc * 16 + r;
            float bv = bias[cc];
#pragma unroll
            for (int i = 0; i < 4; ++i) {
                float v = acc[fr][fc][i] + bv;
                unsigned short hh = f2bf(v);
                long o = (long)(rr + i) * DSZ + cc;
                oh[o] = hh;
                ol[o] = f2bf(v - bf2f(hh));
            }
        }
    }
}

// HG body: 64x64-tile hi-only GEMM, K=768, 2-phase, transposed bf16 out.
// Needs smem of 8192 shorts.
__device__ __forceinline__ void hg_body(
    const unsigned short* __restrict__ hHi, const unsigned short* __restrict__ gTHi,
    unsigned short* __restrict__ HGT, int m0, int n0, unsigned short* smem) {
    unsigned short* sA = smem;           // 2 x 2048
    unsigned short* sB = smem + 4096;    // 2 x 2048
    int tid = threadIdx.x, lane = tid & 63, wave = tid >> 6;
    int wr = wave >> 1, wc = wave & 1;
    int q = lane >> 4, r = lane & 15;
    f32x4 acc[2][2];
#pragma unroll
    for (int i = 0; i < 2; ++i)
#pragma unroll
        for (int j = 0; j < 2; ++j) acc[i][j] = (f32x4){0.f, 0.f, 0.f, 0.f};
    int arow = tid >> 2, ak = (tid & 3) << 3;
    const unsigned short* aP = hHi + (long)(m0 + arow) * HID + ak;
    const unsigned short* bP = gTHi + (long)(n0 + arow) * HID + ak;
    int aOff[2], bOff[2];
#pragma unroll
    for (int f = 0; f < 2; ++f) {
        aOff[f] = (wr * 32 + f * 16 + r) * 32 + q * 8;
        bOff[f] = (wc * 32 + f * 16 + r) * 32 + q * 8;
    }
    auto stage = [&](int k0, int db) {
        gld16(aP + k0, sA + db * 2048 + (wave << 9));
        gld16(bP + k0, sB + db * 2048 + (wave << 9));
    };
    stage(0, 0);
    __syncthreads();
    int db = 0;
    for (int k0 = 0; k0 < HID; k0 += 32) {
        if (k0 + 32 < HID) stage(k0 + 32, db ^ 1);
        const unsigned short* cA = sA + db * 2048;
        const unsigned short* cB = sB + db * 2048;
        bfv8 b0 = *(const bfv8*)(cB + bOff[0]);
        bfv8 b1 = *(const bfv8*)(cB + bOff[1]);
#pragma unroll
        for (int fr = 0; fr < 2; ++fr) {
            bfv8 a = *(const bfv8*)(cA + aOff[fr]);
            acc[fr][0] = __builtin_amdgcn_mfma_f32_16x16x32_bf16(a, b0, acc[fr][0], 0, 0, 0);
            acc[fr][1] = __builtin_amdgcn_mfma_f32_16x16x32_bf16(a, b1, acc[fr][1], 0, 0, 0);
        }
        __syncthreads();
        db ^= 1;
    }
#pragma unroll
    for (int fr = 0; fr < 2; ++fr) {
        int rr = m0 + wr * 32 + fr * 16 + q * 4;
#pragma unroll
        for (int fc = 0; fc < 2; ++fc) {
            int cc = n0 + wc * 32 + fc * 16 + r;
#pragma unroll
            for (int i = 0; i < 4; ++i) {
                int m = rr + i;
                long o = (long)(m >> 7) * ((long)HID * SS) + (long)cc * SS + (m & 127);
                HGT[o] = f2bf(acc[fr][fc][i]);
            }
        }
    }
}

// ---------------------------------------------------------------------------
// P (0..191) + HG (192..383) fused: HG depends only on convec, so it fills
// the 64 CUs that P's 192 blocks leave idle.  Grid (384).
__global__ __launch_bounds__(256) void pgemm_hg(
    const unsigned short* __restrict__ hHi, const unsigned short* __restrict__ hLo,
    const unsigned short* __restrict__ WtHi, const unsigned short* __restrict__ WtLo,
    const float* __restrict__ b1, const float* __restrict__ b2,
    unsigned short* __restrict__ Phi, unsigned short* __restrict__ Plo,
    const unsigned short* __restrict__ gTHi, unsigned short* __restrict__ HGT) {
    __shared__ __align__(16) unsigned short smem[24576];
    int id = blockIdx.x;
    if (id < 192) {
        int which = id / 96, v = id % 96;
        pgemm_body(hHi, hLo, WtHi, WtLo, b1, b2, Phi, Plo,
                   which, (v / 12) * 128, (v % 12) * 64, smem);
    } else {
        int hgid = id - 192;
        hg_body(hHi, gTHi, HGT, (hgid / 12) * 64, (hgid % 12) * 64, smem);
    }
}

// ---------------------------------------------------------------------------
// 128x128 split-precision MFMA core (triple MFMA), fp32 out to Cb.
// 2-phase double-buffered; smem = 32768 shorts.
__device__ __forceinline__ void mfma_core(
    const unsigned short* __restrict__ ah, const unsigned short* __restrict__ al,
    const unsigned short* __restrict__ bh, const unsigned short* __restrict__ bl,
    float* __restrict__ Cb, int K, int kb, int kend, int ldc, int Nvalid,
    int m0, int n0, unsigned short* smem) {
    unsigned short* sAh = smem;              // 2 x 4096
    unsigned short* sAl = smem + 8192;       // 2 x 4096
    unsigned short* sBh = smem + 16384;      // 2 x 4096
    unsigned short* sBl = smem + 24576;      // 2 x 4096
    int tid = threadIdx.x;
    int lane = tid & 63, wave = tid >> 6;
    int wr = wave >> 1, wc = wave & 1;
    int q = lane >> 4, r = lane & 15;

    f32x4 acc[4][4];
#pragma unroll
    for (int i = 0; i < 4; ++i)
#pragma unroll
        for (int j = 0; j < 4; ++j) acc[i][j] = (f32x4){0.f, 0.f, 0.f, 0.f};

    int s0 = tid, s1 = tid + 256;
    int arow0 = s0 >> 2, ak0 = (s0 & 3) << 3;
    int arow1 = s1 >> 2, ak1 = (s1 & 3) << 3;
    const unsigned short* aP0 = ah + (long)(m0 + arow0) * K + ak0;
    const unsigned short* aP1 = ah + (long)(m0 + arow1) * K + ak1;
    bool bok0 = (n0 + arow0) < Nvalid, bok1 = (n0 + arow1) < Nvalid;
    const unsigned short* bP0 = bh + (long)(n0 + arow0) * K + ak0;
    const unsigned short* bP1 = bh + (long)(n0 + arow1) * K + ak1;
    const unsigned short* alP0 = al + (long)(m0 + arow0) * K + ak0;
    const unsigned short* alP1 = al + (long)(m0 + arow1) * K + ak1;
    const unsigned short* blP0 = bl + (long)(n0 + arow0) * K + ak0;
    const unsigned short* blP1 = bl + (long)(n0 + arow1) * K + ak1;

    int aOff[4], bOff[4];
#pragma unroll
    for (int f = 0; f < 4; ++f) {
        aOff[f] = (wr * 64 + f * 16 + r) * 32 + q * 8;
        bOff[f] = (wc * 64 + f * 16 + r) * 32 + q * 8;
    }

    auto stage = [&](int k0, int db) {
        unsigned short* a = sAh + db * 4096;
        unsigned short* al_ = sAl + db * 4096;
        unsigned short* b = sBh + db * 4096;
        unsigned short* bl_ = sBl + db * 4096;
        gld16(aP0 + k0, a + (wave << 9));
        gld16(aP1 + k0, a + 2048 + (wave << 9));
        gld16(alP0 + k0, al_ + (wave << 9));
        gld16(alP1 + k0, al_ + 2048 + (wave << 9));
        if (bok0) gld16(bP0 + k0, b + (wave << 9));
        if (bok1) gld16(bP1 + k0, b + 2048 + (wave << 9));
        if (bok0) gld16(blP0 + k0, bl_ + (wave << 9));
        if (bok1) gld16(blP1 + k0, bl_ + 2048 + (wave << 9));
    };

    stage(kb, 0);
    __syncthreads();
    int db = 0;
    for (int k0 = kb; k0 < kend; k0 += 32) {
        if (k0 + 32 < kend) stage(k0 + 32, db ^ 1);
        const unsigned short* cAh = sAh + db * 4096;
        const unsigned short* cAl = sAl + db * 4096;
        const unsigned short* cBh = sBh + db * 4096;
        const unsigned short* cBl = sBl + db * 4096;
        bfv8 bh_r[4], bl_r[4];
#pragma unroll
        for (int fc = 0; fc < 4; ++fc) {
            bh_r[fc] = *(const bfv8*)(cBh + bOff[fc]);
            bl_r[fc] = *(const bfv8*)(cBl + bOff[fc]);
        }
#pragma unroll
        for (int fr = 0; fr < 4; ++fr) {
            bfv8 a_h = *(const bfv8*)(cAh + aOff[fr]);
            bfv8 a_l = *(const bfv8*)(cAl + aOff[fr]);
#pragma unroll
            for (int fc = 0; fc < 4; ++fc) {
                acc[fr][fc] = __builtin_amdgcn_mfma_f32_16x16x32_bf16(a_h, bh_r[fc], acc[fr][fc], 0, 0, 0);
                acc[fr][fc] = __builtin_amdgcn_mfma_f32_16x16x32_bf16(a_h, bl_r[fc], acc[fr][fc], 0, 0, 0);
                acc[fr][fc] = __builtin_amdgcn_mfma_f32_16x16x32_bf16(a_l, bh_r[fc], acc[fr][fc], 0, 0, 0);
            }
        }
        __syncthreads();
        db ^= 1;
    }
#pragma unroll
    for (int fr = 0; fr < 4; ++fr) {
        int rr = m0 + wr * 64 + fr * 16 + q * 4;
#pragma unroll
        for (int fc = 0; fc < 4; ++fc) {
            int cc = n0 + wc * 64 + fc * 16 + r;
            if (cc < Nvalid) {
#pragma unroll
                for (int i = 0; i < 4; ++i)
                    Cb[(long)(rr + i) * ldc + cc] = acc[fr][fc][i];
            }
        }
    }
}

// ---------------------------------------------------------------------------
// UV (0..63, split 4) + Gram (64..127, split 8).  Grid (128).
__global__ __launch_bounds__(256) void uvgram(
    const unsigned short* __restrict__ Phi, const unsigned short* __restrict__ Plo,
    const unsigned short* __restrict__ EtHi, const unsigned short* __restrict__ EtLo,
    float* __restrict__ UVP, float* __restrict__ GP) {
    const long MN = (long)BB * SS * DSZ;
    const long EN = (long)NTP * DSZ;
    const long UVN = (long)BB * SS * NTP;
    const long BSD = (long)SS * DSZ;
    __shared__ __align__(16) unsigned short smem[32768];
    int id = blockIdx.x;
    if (id < 64) {
        int y = id >> 3, z = id & 7;
        int which = z >> 2, split = z & 3;
        mfma_core(Phi + (long)which * MN, Plo + (long)which * MN,
                  EtHi + (long)which * EN, EtLo + (long)which * EN,
                  UVP + (long)which * 4 * UVN + (long)split * UVN,
                  DSZ, split * 192, split * 192 + 192, NTP, NTP,
                  y * 128, 0, smem);
    } else {
        int g = id - 64;
        int b = g >> 3, split = g & 7;
        mfma_core(Phi + (long)b * BSD, Plo + (long)b * BSD,
                  Phi + MN + (long)b * BSD, Plo + MN + (long)b * BSD,
                  GP + (long)b * 8 * (SS * SS) + (long)split * (SS * SS),
                  DSZ, split * 96, split * 96 + 96, SS, SS,
                  0, 0, smem);
    }
}

// ---------------------------------------------------------------------------
// 64x64-tile bf16 GEMM (hi-only), 2-phase pipelined, fused epilogue.
// OUT==1: bf16 out (+bias)(+relu).  OUT==2: fp32 out (+bias).
template <int OUT>
__global__ __launch_bounds__(256) void gemm64(
    const unsigned short* __restrict__ Ahi, const unsigned short* __restrict__ Bhi,
    const float* __restrict__ bias, unsigned short* __restrict__ Chi,
    float* __restrict__ Cf, int relu, int K, int ldc,
    long sA, long sB, long sC) {
    int batch = blockIdx.z;
    int m0 = blockIdx.y * 64, n0 = blockIdx.x * 64;
    const unsigned short* ah = Ahi + (long)batch * sA;
    const unsigned short* bh = Bhi + (long)batch * sB;

    __shared__ __align__(16) unsigned short sAh[4096], sBh[4096];
    int tid = threadIdx.x;
    int lane = tid & 63, wave = tid >> 6;
    int wr = wave >> 1, wc = wave & 1;
    int q = lane >> 4, r = lane & 15;

    f32x4 acc[2][2];
#pragma unroll
    for (int i = 0; i < 2; ++i)
#pragma unroll
        for (int j = 0; j < 2; ++j) acc[i][j] = (f32x4){0.f, 0.f, 0.f, 0.f};

    int arow = tid >> 2, ak = (tid & 3) << 3;
    const unsigned short* aP = ah + (long)(m0 + arow) * K + ak;
    const unsigned short* bP = bh + (long)(n0 + arow) * K + ak;

    int aOff[2], bOff[2];
#pragma unroll
    for (int f = 0; f < 2; ++f) {
        aOff[f] = (wr * 32 + f * 16 + r) * 32 + q * 8;
        bOff[f] = (wc * 32 + f * 16 + r) * 32 + q * 8;
    }

    auto stage = [&](int k0, int db) {
        gld16(aP + k0, sAh + db * 2048 + (wave << 9));
        gld16(bP + k0, sBh + db * 2048 + (wave << 9));
    };
    stage(0, 0);
    __syncthreads();
    int db = 0;
    for (int k0 = 0; k0 < K; k0 += 32) {
        if (k0 + 32 < K) stage(k0 + 32, db ^ 1);
        const unsigned short* cA = sAh + db * 2048;
        const unsigned short* cB = sBh + db * 2048;
        bfv8 b0 = *(const bfv8*)(cB + bOff[0]);
        bfv8 b1 = *(const bfv8*)(cB + bOff[1]);
#pragma unroll
        for (int fr = 0; fr < 2; ++fr) {
            bfv8 a = *(const bfv8*)(cA + aOff[fr]);
            acc[fr][0] = __builtin_amdgcn_mfma_f32_16x16x32_bf16(a, b0, acc[fr][0], 0, 0, 0);
            acc[fr][1] = __builtin_amdgcn_mfma_f32_16x16x32_bf16(a, b1, acc[fr][1], 0, 0, 0);
        }
        __syncthreads();
        db ^= 1;
    }
#pragma unroll
    for (int fr = 0; fr < 2; ++fr) {
        int rr = m0 + wr * 32 + fr * 16 + q * 4;
#pragma unroll
        for (int fc = 0; fc < 2; ++fc) {
            int cc = n0 + wc * 32 + fc * 16 + r;
            float bv = bias ? bias[cc] : 0.f;
#pragma unroll
            for (int i = 0; i < 4; ++i) {
                float v = acc[fr][fc][i] + bv;
                if constexpr (OUT == 1) {
                    if (relu) v = fmaxf(v, 0.f);
                    Chi[(long)batch * sC + (long)(rr + i) * ldc + cc] = f2bf(v);
                } else {
                    Cf[(long)batch * sC + (long)(rr + i) * ldc + cc] = v;
                }
            }
        }
    }
}

// ---------------------------------------------------------------------------
// relevance (sum 8 Gram partials + 4 UV partials + c) + mask + softmax.
__global__ __launch_bounds__(128) void softmax_kernel(
    const int* __restrict__ dep, const float* __restrict__ Gp,
    const float* __restrict__ Up, const float* __restrict__ cv,
    unsigned short* __restrict__ Ahi) {
    const long UVN = (long)BB * SS * NTP;
    int bi = blockIdx.x;
    int b = bi >> 7;
    int j = threadIdx.x;
    int t = dep[(long)bi * SS + j];
    float r;
    if (t != 0) {
        long gbase = (long)bi * SS + j + (long)b * 7L * SS * SS;
        float g = 0.f;
        for (int s = 0; s < 8; ++s) g += Gp[gbase + (long)s * (SS * SS)];
        float su = 0.f, sv = 0.f;
        long ui = (long)bi * NTP + t;
        long vi = ((long)b * SS + j) * NTP + t;
        for (int s = 0; s < 4; ++s) {
            su += Up[(long)s * UVN + ui];
            sv += Up[(long)(4 + s) * UVN + vi];
        }
        r = g + su + sv + cv[t];
    } else {
        r = NEG;
    }
    float m = r;
    for (int off = 1; off < 64; off <<= 1) m = fmaxf(m, __shfl_xor(m, off));
    __shared__ float smax[2], ssum[2];
    if ((threadIdx.x & 63) == 0) smax[threadIdx.x >> 6] = m;
    __syncthreads();
    m = fmaxf(smax[0], smax[1]);
    float p = expf(r - m);
    float s = p;
    for (int off = 1; off < 64; off <<= 1) s += __shfl_xor(s, off);
    if ((threadIdx.x & 63) == 0) ssum[threadIdx.x >> 6] = s;
    __syncthreads();
    s = ssum[0] + ssum[1];
    Ahi[(long)bi * SS + j] = f2bf(p / s);
}

// ===========================================================================
// Legacy fp32 path (ws-size fallback) — verified in rounds 1-3.
__global__ void e_kernel(const float* __restrict__ table,
                         const float* __restrict__ W1,
                         const float* __restrict__ W2,
                         float* __restrict__ Ef) {
    int idx = blockIdx.x * blockDim.x + threadIdx.x;
    if (idx >= NTP * DSZ) return;
    int t = idx / DSZ, e = idx % DSZ;
    float s1 = 0.f, s2 = 0.f;
    if (t < NT)
        for (int d = 0; d < DEP; ++d) {
            float td = table[t * DEP + d];
            s1 += td * W1[(HID + d) * DSZ + e];
            s2 += td * W2[(HID + d) * DSZ + e];
        }
    const long EN = (long)NTP * DSZ;
    Ef[idx] = s2; Ef[EN + idx] = s1;
}

__global__ void c_kernel(const float* __restrict__ Ef, float* __restrict__ cv) {
    int t = blockIdx.x;
    const long EN = (long)NTP * DSZ;
    float s = 0.f;
    for (int e = threadIdx.x; e < DSZ; e += 256)
        s += Ef[(long)t * DSZ + e] * Ef[EN + (long)t * DSZ + e];
    __shared__ float red[256];
    red[threadIdx.x] = s;
    __syncthreads();
    for (int w = 128; w >= 1; w >>= 1) {
        if (threadIdx.x < w) red[threadIdx.x] += red[threadIdx.x + w];
        __syncthreads();
    }
    if (threadIdx.x == 0) cv[t] = red[0];
}

__device__ __forceinline__ void gemm_body(
    const float* __restrict__ Ab, const float* __restrict__ Bb,
    const float* __restrict__ bias, float* __restrict__ Cb,
    int kbeg, int kend, int lda, int ldb, int ldc,
    int row0, int col0, bool relu) {
    __shared__ float As[16][68];
    __shared__ float Bs[16][68];
    int tx = threadIdx.x & 15, ty = threadIdx.x >> 4;
    float acc[4][4] = {};
    for (int k0 = kbeg; k0 < kend; k0 += 16) {
#pragma unroll
        for (int l = 0; l < 4; ++l) {
            int idx = threadIdx.x + l * 256;
            int r = idx >> 4, kk = idx & 15;
            As[kk][r] = Ab[(long)(row0 + r) * lda + k0 + kk];
            int kk2 = idx >> 6, cc = idx & 63;
            Bs[kk2][cc] = Bb[(long)(k0 + kk2) * ldb + col0 + cc];
        }
        __syncthreads();
#pragma unroll
        for (int kk = 0; kk < 16; ++kk) {
            float4 a4 = *(const float4*)&As[kk][ty * 4];
            float4 b4 = *(const float4*)&Bs[kk][tx * 4];
            float a[4] = {a4.x, a4.y, a4.z, a4.w};
            float b[4] = {b4.x, b4.y, b4.z, b4.w};
#pragma unroll
            for (int i = 0; i < 4; ++i)
#pragma unroll
                for (int j = 0; j < 4; ++j) acc[i][j] += a[i] * b[j];
        }
        __syncthreads();
    }
#pragma unroll
    for (int i = 0; i < 4; ++i) {
        int r = row0 + ty * 4 + i;
#pragma unroll
        for (int j = 0; j < 4; ++j) {
            int c = col0 + tx * 4 + j;
            float v = acc[i][j];
            if (bias) v += bias[c];
            if (relu) v = fmaxf(v, 0.f);
            Cb[(long)r * ldc + c] = v;
        }
    }
}

__global__ __launch_bounds__(256) void gemm_k(
    const float* __restrict__ A, const float* __restrict__ B,
    const float* __restrict__ bias, float* __restrict__ C,
    int K, int nsplit, int lda, int ldb, int ldc,
    long sA, long sB, long sC, long splitStride, int relu) {
    int batch = blockIdx.z / nsplit, split = blockIdx.z % nsplit;
    int kc = K / nsplit;
    const float* Ab = A + (long)batch * sA;
    const float* Bb = B + (long)batch * sB;
    float* Cb = C + (long)batch * sC + (long)split * splitStride;
    gemm_body(Ab, Bb, nsplit == 1 ? bias : nullptr, Cb,
              split * kc, split * kc + kc, lda, ldb, ldc,
              blockIdx.y * 64, blockIdx.x * 64, relu && nsplit == 1);
}

__global__ __launch_bounds__(256) void gram32(
    const float* __restrict__ P1, const float* __restrict__ P2,
    float* __restrict__ Gp) {
    int b = blockIdx.z;
    int i0 = blockIdx.y * 32, j0 = blockIdx.x * 32;
    __shared__ float As[32][33];
    __shared__ float Bs[32][33];
    const float* p1 = P1 + (long)b * SS * DSZ;
    const float* p2 = P2 + (long)b * SS * DSZ;
    int tx = threadIdx.x % 32, ty = threadIdx.x / 32;
    float acc[4] = {0.f, 0.f, 0.f, 0.f};
    for (int k0 = 0; k0 < DSZ; k0 += 32) {
#pragma unroll
        for (int l = 0; l < 4; ++l) {
            int idx = threadIdx.x + l * 256;
            int r = idx / 32, kk = idx % 32;
            As[kk][r] = p1[(long)(i0 + r) * DSZ + k0 + kk];
            Bs[kk][r] = p2[(long)(j0 + r) * DSZ + k0 + kk];
        }
        __syncthreads();
#pragma unroll
        for (int kk = 0; kk < 32; ++kk) {
            float bv = Bs[kk][tx];
#pragma unroll
            for (int i = 0; i < 4; ++i) acc[i] += As[kk][ty * 4 + i] * bv;
        }
        __syncthreads();
    }
#pragma unroll
    for (int i = 0; i < 4; ++i)
        Gp[((long)b * SS + i0 + ty * 4 + i) * SS + j0 + tx] = acc[i];
}

__global__ __launch_bounds__(256) void uv_kernel(
    const float* __restrict__ P1, const float* __restrict__ P2,
    const float* __restrict__ E1, const float* __restrict__ E2,
    const float* __restrict__ cv, float* __restrict__ U, float* __restrict__ V) {
    int bs = blockIdx.x;
    __shared__ float p1[DSZ], p2[DSZ];
    for (int e = threadIdx.x; e < DSZ; e += 256) {
        p1[e] = P1[(long)bs * DSZ + e];
        p2[e] = P2[(long)bs * DSZ + e];
    }
    __syncthreads();
    int wave = threadIdx.x / 64, lane = threadIdx.x % 64;
    for (int t = wave; t < NT; t += 4) {
        float su = 0.f, sv = 0.f;
        for (int e = lane; e < DSZ; e += 64) {
            su += p1[e] * E2[(long)t * DSZ + e];
            sv += p2[e] * E1[(long)t * DSZ + e];
        }
        for (int off = 32; off >= 1; off >>= 1) {
            su += __shfl_down(su, off);
            sv += __shfl_down(sv, off);
        }
        if (lane == 0) {
            U[(long)bs * NTP + t] = su;
            V[(long)bs * NTP + t] = sv + cv[t];
        }
    }
}

__global__ __launch_bounds__(128) void softmax_fb(
    const int* __restrict__ dep, const float* __restrict__ G,
    const float* __restrict__ U, const float* __restrict__ V,
    float* __restrict__ A) {
    int bi = blockIdx.x;
    int b = bi >> 7;
    int j = threadIdx.x;
    int t = dep[(long)bi * SS + j];
    float r;
    if (t != 0)
        r = G[(long)bi * SS + j] + U[(long)bi * NTP + t] + V[((long)b * SS + j) * NTP + t];
    else
        r = NEG;
    float m = r;
    for (int off = 1; off < 64; off <<= 1) m = fmaxf(m, __shfl_xor(m, off));
    __shared__ float smax[2], ssum[2];
    if ((threadIdx.x & 63) == 0) smax[threadIdx.x >> 6] = m;
    __syncthreads();
    m = fmaxf(smax[0], smax[1]);
    float p = expf(r - m);
    float s = p;
    for (int off = 1; off < 64; off <<= 1) s += __shfl_xor(s, off);
    if ((threadIdx.x & 63) == 0) ssum[threadIdx.x >> 6] = s;
    __syncthreads();
    s = ssum[0] + ssum[1];
    A[(long)bi * SS + j] = p / s;
}

// ---------------------------------------------------------------------------
extern "C" void kernel_launch(void* const* d_in, const int* in_sizes, int n_in,
                              void* d_out, int out_size, void* d_ws, size_t ws_size,
                              hipStream_t stream) {
    const float* h      = (const float*)d_in[0];
    const int*   dep    = (const int*)d_in[1];
    const float* table  = (const float*)d_in[2];
    const float* W1_w   = (const float*)d_in[3];
    const float* W1_b   = (const float*)d_in[4];
    const float* W2_w   = (const float*)d_in[5];
    const float* W2_b   = (const float*)d_in[6];
    const float* gcn_w  = (const float*)d_in[7];
    const float* gcn_b  = (const float*)d_in[8];
    const float* Wo_w   = (const float*)d_in[9];
    const float* Wo_b   = (const float*)d_in[10];
    float* out = (float*)d_out;

    const long nBS = (long)BB * SS;        // 1024
    const long MN  = nBS * DSZ;            // 786432
    const long BSS = (long)BB * SS * SS;   // 131072
    const long UVN = nBS * NTP;            // 49152
    const long EN  = (long)NTP * DSZ;      // 36864
    const long WN  = (long)DSZ * HID;      // 589824
    const long BSD = (long)SS * DSZ;       // 98304

    char* base = (char*)d_ws;
    size_t off = 0;
    auto alloc = [&](size_t bytes) -> void* {
        void* p = base + off;
        off += (bytes + 255) & ~(size_t)255;
        return p;
    };

    float* CV    = (float*)alloc(256);
    float* GP    = (float*)alloc(8 * BSS * 4);   // Gram partials
    float* UVP   = (float*)alloc(8 * UVN * 4);   // UV partials
    unsigned short* EtHi = (unsigned short*)alloc(2 * EN * 2);
    unsigned short* EtLo = (unsigned short*)alloc(2 * EN * 2);
    unsigned short* hHi  = (unsigned short*)alloc(MN * 2);
    unsigned short* hLo  = (unsigned short*)alloc(MN * 2);
    unsigned short* WtHi = (unsigned short*)alloc(2 * WN * 2);
    unsigned short* WtLo = (unsigned short*)alloc(2 * WN * 2);
    unsigned short* gTHi = (unsigned short*)alloc(WN * 2);
    unsigned short* oTHi = (unsigned short*)alloc(WN * 2);
    unsigned short* Phi  = (unsigned short*)alloc(2 * MN * 2);
    unsigned short* Plo  = (unsigned short*)alloc(2 * MN * 2);
    unsigned short* AmHi = (unsigned short*)alloc(BSS * 2);
    unsigned short* HGT  = (unsigned short*)alloc(MN * 2);   // [8][768][128]
    unsigned short* HSHi = (unsigned short*)alloc(MN * 2);
    size_t needBig = off;

    if (ws_size >= needBig) {
        // 1. conversions + E + c  (one launch)
        convec<<<dim3(24, 24, 13), 256, 0, stream>>>(
            h, table, W1_w, W2_w, gcn_w, Wo_w,
            hHi, hLo, WtHi, WtLo, gTHi, oTHi, EtHi, EtLo, CV);
        // 2. P1/P2 (192 blk) + HG (192 blk) fused -> 384 blocks
        pgemm_hg<<<384, 256, 0, stream>>>(
            hHi, hLo, WtHi, WtLo, W1_b, W2_b, Phi, Plo, gTHi, HGT);
        // 3. UV + Gram (64 + 64 = 128 blocks)
        uvgram<<<128, 256, 0, stream>>>(Phi, Plo, EtHi, EtLo, UVP, GP);
        // 4. softmax -> bf16 A
        softmax_kernel<<<nBS, 128, 0, stream>>>(dep, GP, UVP, CV, AmHi);
        // 5. HSYN = relu(A @ HG^T + gcn_b): batched K=128 -> 192 blk
        gemm64<1><<<dim3(12, 2, 8), 256, 0, stream>>>(
            AmHi, HGT, gcn_b, HSHi, nullptr, 1, SS, HID,
            (long)SS * SS, (long)HID * SS, BSD);
        // 6. out = HSYN @ Wo + b -> 192 blk, fp32 direct
        gemm64<2><<<dim3(12, 16, 1), 256, 0, stream>>>(
            HSHi, oTHi, Wo_b, nullptr, out, 0, DSZ, HID, 0, 0, 0);
    } else {
        // Fallback: verified fp32 nsplit=1 path, compact layout.
        float* ws = (float*)d_ws;
        long o2 = 0;
        float* Ef2  = ws + o2; o2 += 2 * EN;
        float* CV2  = ws + o2; o2 += 64;
        float* P1   = ws + o2; o2 += MN;
        float* P2   = ws + o2; o2 += MN;
        float* Uf   = ws + o2; o2 += UVN;
        float* Vf   = ws + o2; o2 += UVN;
        float* G    = ws + o2; o2 += BSS;
        float* Amat = ws + o2; o2 += BSS;
        float* AGG  = ws + o2; o2 += MN;
        float* HSYN = ws + o2; o2 += MN;

        e_kernel<<<(NTP * DSZ + 255) / 256, 256, 0, stream>>>(table, W1_w, W2_w, Ef2);
        c_kernel<<<NT, 256, 0, stream>>>(Ef2, CV2);
        gemm_k<<<dim3(DSZ / 64, nBS / 64, 1), 256, 0, stream>>>(
            h, W1_w, W1_b, P1, HID, 1, HID, DSZ, DSZ, 0, 0, 0, 0, 0);
        gemm_k<<<dim3(DSZ / 64, nBS / 64, 1), 256, 0, stream>>>(
            h, W2_w, W2_b, P2, HID, 1, HID, DSZ, DSZ, 0, 0, 0, 0, 0);
        uv_kernel<<<nBS, 256, 0, stream>>>(P1, P2, Ef2 + EN, Ef2, CV2, Uf, Vf);
        gram32<<<dim3(SS / 32, SS / 32, BB), 256, 0, stream>>>(P1, P2, G);
        softmax_fb<<<nBS, 128, 0, stream>>>(dep, G, Uf, Vf, Amat);
        gemm_k<<<dim3(HID / 64, SS / 64, BB), 256, 0, stream>>>(
            Amat, h, nullptr, AGG, SS, 1, SS, HID, HID,
            (long)SS * SS, BSD, BSD, 0, 0);
        gemm_k<<<dim3(HID / 64, nBS / 64, 1), 256, 0, stream>>>(
            AGG, gcn_w, gcn_b, HSYN, HID, 1, HID, HID, HID, 0, 0, 0, 0, 1);
        gemm_k<<<dim3(HID / 64, nBS / 64, 1), 256, 0, stream>>>(
            HSYN, Wo_w, Wo_b, out, DSZ, 1, DSZ, HID, HID, 0, 0, 0, 0, 0);
    }
}